// Round 19
// baseline (1882.124 us; speedup 1.0000x reference)
//
#include <hip/hip_runtime.h>
#include <math.h>

typedef short s16x4 __attribute__((ext_vector_type(4)));
typedef short s16x8 __attribute__((ext_vector_type(8)));
typedef float f32x4 __attribute__((ext_vector_type(4)));
typedef unsigned short us;
typedef unsigned long long ull;

#define WAITVM(N) do { asm volatile("s_waitcnt vmcnt(" #N ")" ::: "memory"); __builtin_amdgcn_sched_barrier(0); } while (0)

namespace {
constexpr int T = 80, Fdim = 32, H = 512, OSTR = 34;
constexpr int CH = 2048;   // us elements per chunk (fp16)

__device__ __forceinline__ us f2h(float f) {
  union { _Float16 h; us u; } x; x.h = (_Float16)f; return x.u;
}
__device__ __forceinline__ float sigf(float v) { return 1.f / (1.f + expf(-v)); }
__device__ __forceinline__ float geluf(float v) {
  return 0.5f * v * (1.f + erff(v * 0.70710678118654752f));
}

__device__ __forceinline__ ull ald8(const void* p) {
  return __hip_atomic_load((const ull*)p, __ATOMIC_RELAXED, __HIP_MEMORY_SCOPE_AGENT);
}
__device__ __forceinline__ void ast8(void* p, ull v) {
  __hip_atomic_store((ull*)p, v, __ATOMIC_RELAXED, __HIP_MEMORY_SCOPE_AGENT);
}
__device__ __forceinline__ void ast4f(float* p, float v) {
  __hip_atomic_store(p, v, __ATOMIC_RELAXED, __HIP_MEMORY_SCOPE_AGENT);
}

union U8 { ull u; s16x4 v4; float f[2]; };
union S8 { s16x8 v; ull u[2]; };

struct SetA { ull a0, a1; };
struct SetB { s16x8 b1, b0; };
struct HSetA { ull a0; };
struct HSetB { s16x8 b0, b1; };

// ---------------- weight pre-pack: single fp16, fragment-linear ----------------
__global__ __launch_bounds__(256)
void pack_w_kernel(const float* __restrict__ w1, const float* __restrict__ w2,
                   int K1, int K2, int NKC, int head, us* __restrict__ dst) {
  int bid = blockIdx.x;
  int jb = bid / NKC, kc = bid % NKC;
  int tid = threadIdx.x;
  int strip = tid >> 6, l = tid & 63;
  int nl = l & 15, kg = l >> 4;
  int n = head ? (jb * 64 + strip * 16 + nl) : (strip * 512 + jb * 16 + nl);
  s16x8 h8;
  #pragma unroll
  for (int i = 0; i < 8; ++i) {
    int k = kc * 32 + kg * 8 + i;
    float v = (k < K1) ? w1[(size_t)n * K1 + k] : w2[(size_t)n * K2 + (k - K1)];
    h8[i] = (short)f2h(v);
  }
  *(s16x8*)&dst[(size_t)bid * CH + strip * 512 + l * 8] = h8;
}

__global__ __launch_bounds__(256)
void bsum_kernel(const float* bi0, const float* bh0, const float* bi1, const float* bh1,
                 float* bs0, float* bs1) {
  int i = blockIdx.x * 256 + threadIdx.x;
  if (i < 2048) bs0[i] = bi0[i] + bh0[i];
  else { int j = i - 2048; bs1[j] = bi1[j] + bh1[j]; }
}

// ---------------- persistent whole-model kernel ----------------
// 256 WGs = 8 groups (64 rows) x 32 WGs (16 h-cols). fp16 datapath.
// Fused phases: per-chunk producer flags (2 writers/chunk) at entry,
// all-32 wait deferred to pre-epilogue. Heads keep full entry wait.
__global__ __launch_bounds__(256, 1)
void persist_kernel(const float* __restrict__ x,
                    const us* __restrict__ Wp0, const us* __restrict__ Wp1,
                    const us* __restrict__ Wpf1, const us* __restrict__ Wpf2,
                    const float* __restrict__ bs0, const float* __restrict__ bs1,
                    const float* __restrict__ fc1_b, const float* __restrict__ fc2_b,
                    const float* __restrict__ fc3_w, const float* __restrict__ fc3_b,
                    us* hp0_0, us* hp0_1, us* hp1_0, us* hp1_1,
                    float* c0, float* c1, us* y1p,
                    float* out, int* cnt)
{
  __shared__ __align__(16) us Ash[8][2048];
  __shared__ __align__(16) float Gs[4][64][16];

  const int tid = threadIdx.x;
  const int bid = blockIdx.x;
  const int w = tid >> 6, l = tid & 63;
  const int m = bid >> 5;                      // group 0..7 (64 rows)
  const int lb = bid & 31;                     // group-local WG id
  const int jb = (lb & 7) * 4 + (lb >> 3);     // h-col slice 0..31
  const int row0 = m * 64;
  const int j0 = jb * 16;
  const int base31 = j0 & 31;

  const us* WpJ0 = Wp0 + (size_t)jb * 17 * CH;
  const us* WpJ1 = Wp1 + (size_t)jb * 32 * CH;

  int ph = 0;
  auto garrive = [&]() {
    ++ph;
    WAITVM(0);
    __syncthreads();
    if (tid == 0)
      __hip_atomic_store(&cnt[m * 512 + lb * 16], ph, __ATOMIC_RELEASE,
                         __HIP_MEMORY_SCOPE_AGENT);
  };
  // full-group wait (>= need); caller relies on trailing __syncthreads
  auto gwaitall = [&](int need) {
    if (tid < 32) {
      while (__hip_atomic_load(&cnt[m * 512 + tid * 16], __ATOMIC_RELAXED,
                               __HIP_MEMORY_SCOPE_AGENT) < need)
        __builtin_amdgcn_s_sleep(1);
      __builtin_amdgcn_fence(__ATOMIC_ACQUIRE, "workgroup");
    }
    __syncthreads();
  };
  // per-chunk writer flags: chunks c0..c0+cN-1 (< hi), writers jb=2(c&15)(+1)
  auto pollH = [&](int c0, int cN, int hi, int need) {
    if (tid < 2 * cN) {
      int c = c0 + (tid >> 1);
      if (c < hi) {
        int cc = c & 15;
        int jbw = 2 * cc + (tid & 1);
        int lbw = ((jbw & 3) << 3) + (jbw >> 2);
        while (__hip_atomic_load(&cnt[m * 512 + lbw * 16], __ATOMIC_RELAXED,
                                 __HIP_MEMORY_SCOPE_AGENT) < need)
          __builtin_amdgcn_s_sleep(1);
        __builtin_amdgcn_fence(__ATOMIC_ACQUIRE, "workgroup");
      }
    }
  };

  // ---------- fused LSTM phase: {L1(t-1) if DO1} + {L0(t) if DO0} ----------
  // d0/d1: flag offsets (vs current ph) required for chunks <16 / >=16.
  // seg1first: run chunks 16..31 first (their data is older).
  auto fused = [&](bool DO1, bool DO0, int t, bool use_fb, int kidx,
                   int d0, int d1, bool seg1first) {
    const us* h0prev = ((t + 1) & 1) ? hp0_1 : hp0_0;
    const us* h1prev = (t & 1) ? hp1_1 : hp1_0;
    us* h1w = ((t + 1) & 1) ? hp1_1 : hp1_0;
    us* h0w = (t & 1) ? hp0_1 : hp0_0;

    f32x4 acc0[4], acc1[4];
    #pragma unroll
    for (int mf = 0; mf < 4; ++mf) {
      acc0[mf] = {0.f, 0.f, 0.f, 0.f};
      acc1[mf] = {0.f, 0.f, 0.f, 0.f};
    }
    const int NP = DO1 ? 32 : 16;
    const int need0 = ph + d0, need1 = ph + d1;
    SetA A0s, A1s, A2s, A3s;
    SetB B0s, B1s, B2s, B3s;

    auto issA = [&](int c, SetA& R, int hi) {
      if (c >= hi) return;
      const us* a = ((c < 16) ? h0prev : h1prev) + (size_t)(m * 16 + (c & 15)) * CH;
      R.a0 = ald8(a + tid * 8);
      R.a1 = ald8(a + tid * 8 + 4);
    };
    auto issB = [&](int c, SetB& R, int hi) {
      if (c >= hi) return;
      if (DO1) R.b1 = *(const s16x8*)(WpJ1 + (size_t)c * CH + w * 512 + l * 8);
      if (DO0 && c < 16)
        R.b0 = *(const s16x8*)(WpJ0 + (size_t)(c + 1) * CH + w * 512 + l * 8);
    };
    auto wrtA = [&](int c, SetA& R, int hi) {
      if (c >= hi) return;
      int sl = c & 7;
      *(ull*)&Ash[sl][tid * 8] = R.a0;
      *(ull*)&Ash[sl][tid * 8 + 4] = R.a1;
    };
    auto lcomp = [&](int kc, SetB& B, bool c1on, bool c0on) {
      int sl = kc & 7;
      #pragma unroll
      for (int mf = 0; mf < 4; ++mf) {
        s16x8 Ah = *(const s16x8*)&Ash[sl][mf * 512 + l * 8];
        if (c1on)
          acc1[mf] = __builtin_amdgcn_mfma_f32_16x16x32_f16(Ah, B.b1, acc1[mf], 0, 0, 0);
        if (c0on)
          acc0[mf] = __builtin_amdgcn_mfma_f32_16x16x32_f16(Ah, B.b0, acc0[mf], 0, 0, 0);
      }
    };

    auto runseg = [&](int lo, int hi, int need) {
      pollH(lo, 8, hi, need);
      __syncthreads();
      issA(lo + 0, A0s, hi); issA(lo + 1, A1s, hi);
      issA(lo + 2, A2s, hi); issA(lo + 3, A3s, hi);
      wrtA(lo + 0, A0s, hi); wrtA(lo + 1, A1s, hi);
      wrtA(lo + 2, A2s, hi); wrtA(lo + 3, A3s, hi);
      issA(lo + 4, A0s, hi); issA(lo + 5, A1s, hi);
      issA(lo + 6, A2s, hi); issA(lo + 7, A3s, hi);
      __syncthreads();
      for (int base = lo; base < hi; base += 4) {
        { int kc = base + 0; lcomp(kc, B0s, DO1, DO0 && kc < 16); issB(kc + 4, B0s, hi); }
        { int kc = base + 1; lcomp(kc, B1s, DO1, DO0 && kc < 16); issB(kc + 4, B1s, hi); }
        { int kc = base + 2; lcomp(kc, B2s, DO1, DO0 && kc < 16); issB(kc + 4, B2s, hi); }
        { int kc = base + 3; lcomp(kc, B3s, DO1, DO0 && kc < 16); issB(kc + 4, B3s, hi); }
        pollH(base + 8, 4, hi, need);
        __syncthreads();
        wrtA(base + 4, A0s, hi); wrtA(base + 5, A1s, hi);
        wrtA(base + 6, A2s, hi); wrtA(base + 7, A3s, hi);
        issA(base + 8, A0s, hi); issA(base + 9, A1s, hi);
        issA(base + 10, A2s, hi); issA(base + 11, A3s, hi);
        __syncthreads();
      }
    };

    if (DO1 && seg1first) {
      issB(16, B0s, 32); issB(17, B1s, 32); issB(18, B2s, 32); issB(19, B3s, 32);
      runseg(16, 32, need1);
      issB(0, B0s, 16); issB(1, B1s, 16); issB(2, B2s, 16); issB(3, B3s, 16);
      runseg(0, 16, need0);
    } else if (DO1) {
      // warmup: need0 == need1, single pass
      issB(0, B0s, 32); issB(1, B1s, 32); issB(2, B2s, 32); issB(3, B3s, 32);
      runseg(0, 32, need0);
    } else {
      issB(0, B0s, 16); issB(1, B1s, 16); issB(2, B2s, 16); issB(3, B3s, 16);
      runseg(0, 16, need0);
    }

    bool waited = false;
    if (DO0) {  // x chunk (L0 weight chunk 0)
      if (use_fb) { gwaitall(ph); waited = true; }   // feedback needs prev phase done
      SetB Bx;
      Bx.b0 = *(const s16x8*)(WpJ0 + w * 512 + l * 8);
      int srow = tid >> 2, skg = tid & 3;
      const float* xp = x + (size_t)(row0 + srow) * (T * Fdim) + (size_t)t * Fdim + skg * 8;
      float v[8];
      #pragma unroll
      for (int i = 0; i < 8; ++i) v[i] = xp[i];
      if (use_fb && skg == 0) {
        const float* op = out + (size_t)(row0 + srow) * OSTR + kidx * 2;
        v[4] = __hip_atomic_load(op, __ATOMIC_RELAXED, __HIP_MEMORY_SCOPE_AGENT);
        v[5] = __hip_atomic_load(op + 1, __ATOMIC_RELAXED, __HIP_MEMORY_SCOPE_AGENT);
      }
      s16x8 h8;
      #pragma unroll
      for (int i = 0; i < 8; ++i) h8[i] = (short)f2h(v[i]);
      int slane = skg * 16 + (srow & 15), smf = srow >> 4;
      *(s16x8*)&Ash[0][smf * 512 + slane * 8] = h8;
      __syncthreads();
      lcomp(0, Bx, false, true);
    }

    if (!waited) gwaitall(ph);   // WAR guard: all WGs left previous phase

    // epilogue: stash gates -> cell -> packed coherent h write (fp16)
    auto epi = [&](f32x4* acc, const float* bsum, float* cst, us* hw) {
      __syncthreads();
      float bsv = bsum[w * 512 + j0 + (l & 15)];
      #pragma unroll
      for (int mf = 0; mf < 4; ++mf)
        #pragma unroll
        for (int r = 0; r < 4; ++r)
          Gs[w][mf * 16 + (l >> 4) * 4 + r][l & 15] = acc[mf][r] + bsv;
      __syncthreads();
      int r = tid >> 2, sub = tid & 3, cc0 = sub * 4;
      float gvi[4], gvf[4], gvg[4], gvo[4], cv[4], cn[4], hv[4];
      #pragma unroll
      for (int q = 0; q < 4; ++q) {
        gvi[q] = Gs[0][r][cc0 + q]; gvf[q] = Gs[1][r][cc0 + q];
        gvg[q] = Gs[2][r][cc0 + q]; gvo[q] = Gs[3][r][cc0 + q];
      }
      size_t cix = (size_t)(row0 + r) * H + j0 + cc0;
      float4 cold = *(const float4*)&cst[cix];
      cv[0] = cold.x; cv[1] = cold.y; cv[2] = cold.z; cv[3] = cold.w;
      #pragma unroll
      for (int q = 0; q < 4; ++q) {
        float c2 = sigf(gvf[q]) * cv[q] + sigf(gvi[q]) * tanhf(gvg[q]);
        cn[q] = c2;
        hv[q] = sigf(gvo[q]) * tanhf(c2);
      }
      *(float4*)&cst[cix] = make_float4(cn[0], cn[1], cn[2], cn[3]);
      int kk = base31 + cc0;
      int kg = kk >> 3, i0 = kk & 7;
      int mf = r >> 4;
      int lane2 = kg * 16 + (r & 15);
      us* bb = hw + (size_t)(m * 16 + (j0 >> 5)) * CH;
      U8 hh;
      #pragma unroll
      for (int q = 0; q < 4; ++q) hh.v4[q] = (short)f2h(hv[q]);
      ast8(bb + (size_t)mf * 512 + lane2 * 8 + i0, hh.u);
      __syncthreads();
    };
    if (DO1) epi(acc1, bs1, c1, h1w);
    if (DO0) epi(acc0, bs0, c0, h0w);
  };

  // ---------- head GEMM: 16 of 32 WGs, 32 rows x 64 cols (r18-identical) ----------
  auto headg = [&](const us* apack, const us* Wp, const float* bias,
                   us* yp, int kidx) {
    if (lb < 16) {
      const int mhl = lb >> 3, cb = lb & 7;
      const int hrow0 = row0 + mhl * 32, hj0 = cb * 64;
      const int wm = w >> 1, wn = w & 1;
      f32x4 hacc[2];
      hacc[0] = {0.f, 0.f, 0.f, 0.f};
      hacc[1] = {0.f, 0.f, 0.f, 0.f};
      HSetA HA0, HA1, HA2, HA3;
      HSetB HB0, HB1;
      auto hissA = [&](int c, HSetA& R) {
        if (c >= 16) return;
        const us* a = apack + (size_t)(m * 16 + c) * CH + mhl * 1024;
        R.a0 = ald8(a + tid * 4);
      };
      auto hissB = [&](int c, HSetB& R) {
        if (c >= 16) return;
        const us* b = Wp + (size_t)(cb * 16 + c) * CH + wn * 1024 + l * 8;
        R.b0 = *(const s16x8*)(b);
        R.b1 = *(const s16x8*)(b + 512);
      };
      auto hwrtA = [&](int c, HSetA& R) {
        if (c >= 16) return;
        int sl = c % 3;
        *(ull*)&Ash[sl][tid * 4] = R.a0;
      };
      auto hcmp = [&](int sl, HSetB& B) {
        s16x8 Ah = *(const s16x8*)&Ash[sl][wm * 512 + l * 8];
        hacc[0] = __builtin_amdgcn_mfma_f32_16x16x32_f16(Ah, B.b0, hacc[0], 0, 0, 0);
        hacc[1] = __builtin_amdgcn_mfma_f32_16x16x32_f16(Ah, B.b1, hacc[1], 0, 0, 0);
      };
      hissA(0, HA0); hissA(1, HA1); hissA(2, HA2); hissA(3, HA3);
      hwrtA(0, HA0); hissA(4, HA0);
      hwrtA(1, HA1); hissA(5, HA1);
      hissB(0, HB0); hissB(1, HB1);
      __syncthreads();
      for (int base = 0; base < 16; base += 4) {
        { int kc = base + 0; hcmp(kc % 3, HB0); hissB(kc + 2, HB0);
          hwrtA(kc + 2, HA2); hissA(kc + 6, HA2); __syncthreads(); }
        { int kc = base + 1; hcmp(kc % 3, HB1); hissB(kc + 2, HB1);
          hwrtA(kc + 2, HA3); hissA(kc + 6, HA3); __syncthreads(); }
        { int kc = base + 2; hcmp(kc % 3, HB0); hissB(kc + 2, HB0);
          hwrtA(kc + 2, HA0); hissA(kc + 6, HA0); __syncthreads(); }
        { int kc = base + 3; hcmp(kc % 3, HB1); hissB(kc + 2, HB1);
          hwrtA(kc + 2, HA1); hissA(kc + 6, HA1); __syncthreads(); }
      }
      __syncthreads();
      float* GsF = (float*)Gs;
      #pragma unroll
      for (int nf = 0; nf < 2; ++nf)
        #pragma unroll
        for (int rq = 0; rq < 4; ++rq) {
          int rr = wm * 16 + (l >> 4) * 4 + rq;
          int ccl = wn * 32 + nf * 16 + (l & 15);
          GsF[rr * 64 + ccl] = geluf(hacc[nf][rq] + bias[hj0 + ccl]);
        }
      __syncthreads();
      if (yp) {
        int chunk = tid >> 7, tt = tid & 127;
        int mf_loc = tt >> 6, lane = tt & 63;
        int row = mf_loc * 16 + (lane & 15);
        int kg = lane >> 4;
        S8 hv;
        #pragma unroll
        for (int i = 0; i < 8; ++i)
          hv.v[i] = (short)f2h(GsF[row * 64 + chunk * 32 + kg * 8 + i]);
        us* dst = yp + ((size_t)m * 16 + (cb * 2 + chunk)) * CH;
        ast8(dst + (size_t)(mhl * 2 + mf_loc) * 512 + lane * 8, hv.u[0]);
        ast8(dst + (size_t)(mhl * 2 + mf_loc) * 512 + lane * 8 + 4, hv.u[1]);
      } else {
        int r = tid >> 3, cg = tid & 7;
        float p0 = 0.f, p1 = 0.f;
        #pragma unroll
        for (int i = 0; i < 8; ++i) {
          float yv = GsF[r * 64 + cg * 8 + i];
          int col = hj0 + cg * 8 + i;
          p0 += yv * fc3_w[col];
          p1 += yv * fc3_w[512 + col];
        }
        #pragma unroll
        for (int d = 4; d > 0; d >>= 1) {
          p0 += __shfl_down(p0, d, 8);
          p1 += __shfl_down(p1, d, 8);
        }
        if (cg == 0) {
          atomicAdd(out + (size_t)(hrow0 + r) * OSTR + kidx * 2, p0);
          atomicAdd(out + (size_t)(hrow0 + r) * OSTR + kidx * 2 + 1, p1);
        }
      }
      __syncthreads();
    }
  };

  auto h1buf = [&](int t) { return (t & 1) ? hp1_1 : hp1_0; };

  // ================= schedule (8 independent groups) =================
  // warmup: per-chunk flags (need = ph for both segments)
  fused(false, true, 0, false, 0, 0, 0, false); garrive();
  for (int t = 1; t < 64; ++t) { fused(true, true, t, false, 0, 0, 0, false); garrive(); }
  // L1(63): h0(63) prev phase (d0=0), h1(62) two back (d1=-1); old segment first
  fused(true, false, 64, false, 0, 0, -1, true); garrive();

  for (int kidx = 0; kidx < 17; ++kidx) {
    const us* h1cur = h1buf(63 + kidx);
    gwaitall(ph);
    headg(h1cur, Wpf1, fc1_b, y1p, kidx);
    if (lb == 16 && tid < 128) {
      int r2 = tid >> 1, o = tid & 1;
      ast4f(out + (size_t)(row0 + r2) * OSTR + kidx * 2 + o, fc3_b[o]);
    }
    garrive();
    gwaitall(ph);
    headg(y1p, Wpf2, fc2_b, nullptr, kidx);
    garrive();
    if (kidx < 16) {
      // AR L0: h0 chunks 4 phases old (d0=-3); feedback gated inside
      fused(false, true, 64 + kidx, true, kidx, -3, 0, false); garrive();
      // AR L1: h0 prev phase (d0=0), h1 4 phases old (d1=-3); old segment first
      fused(true, false, 65 + kidx, false, 0, 0, -3, true); garrive();
    }
  }
}

} // namespace

extern "C" void kernel_launch(void* const* d_in, const int* in_sizes, int n_in,
                              void* d_out, int out_size, void* d_ws, size_t ws_size,
                              hipStream_t stream) {
  const float* x     = (const float*)d_in[0];
  const float* w_ih0 = (const float*)d_in[1];
  const float* w_hh0 = (const float*)d_in[2];
  const float* b_ih0 = (const float*)d_in[3];
  const float* b_hh0 = (const float*)d_in[4];
  const float* w_ih1 = (const float*)d_in[5];
  const float* w_hh1 = (const float*)d_in[6];
  const float* b_ih1 = (const float*)d_in[7];
  const float* b_hh1 = (const float*)d_in[8];
  const float* fc1_w = (const float*)d_in[9];
  const float* fc1_b = (const float*)d_in[10];
  const float* fc2_w = (const float*)d_in[11];
  const float* fc2_b = (const float*)d_in[12];
  const float* fc3_w = (const float*)d_in[13];
  const float* fc3_b = (const float*)d_in[14];
  float* out = (float*)d_out;
  char* wsb = (char*)d_ws;

  constexpr size_t KB = 1024;
  constexpr size_t O_WP0  = 0;                          // 32*17*4KB
  constexpr size_t O_WP1  = 2228224;                    // 32*32*4KB
  constexpr size_t O_WPF1 = O_WP1 + 4194304;
  constexpr size_t O_WPF2 = O_WPF1 + 524288;
  constexpr size_t O_BS0  = O_WPF2 + 524288;
  constexpr size_t O_BS1  = O_BS0 + 8192;
  constexpr size_t O_CNT  = O_BS1 + 8192;               // flags 16 KB
  constexpr size_t O_HP0B = O_CNT + 16384;              // hp0_1 (zeroed)
  constexpr size_t O_HP1B = O_HP0B + 512 * KB;          // hp1_1 (zeroed)
  constexpr size_t O_C0   = O_HP1B + 512 * KB;          // c0 (zeroed)
  constexpr size_t O_C1   = O_C0 + 1024 * KB;           // c1 (zeroed)
  constexpr size_t O_HP0A = O_C1 + 1024 * KB;
  constexpr size_t O_HP1A = O_HP0A + 512 * KB;
  constexpr size_t O_Y1P  = O_HP1A + 512 * KB;

  us* Wp0  = (us*)(wsb + O_WP0);
  us* Wp1  = (us*)(wsb + O_WP1);
  us* Wpf1 = (us*)(wsb + O_WPF1);
  us* Wpf2 = (us*)(wsb + O_WPF2);
  float* bs0 = (float*)(wsb + O_BS0);
  float* bs1 = (float*)(wsb + O_BS1);
  int* cnt   = (int*)(wsb + O_CNT);
  us* hp0_1 = (us*)(wsb + O_HP0B);
  us* hp1_1 = (us*)(wsb + O_HP1B);
  float* c0 = (float*)(wsb + O_C0);
  float* c1 = (float*)(wsb + O_C1);
  us* hp0_0 = (us*)(wsb + O_HP0A);
  us* hp1_0 = (us*)(wsb + O_HP1A);
  us* y1p   = (us*)(wsb + O_Y1P);

  pack_w_kernel<<<dim3(32 * 17), 256, 0, stream>>>(w_ih0, w_hh0, 32, 512, 17, 0, Wp0);
  pack_w_kernel<<<dim3(32 * 32), 256, 0, stream>>>(w_ih1, w_hh1, 512, 512, 32, 0, Wp1);
  pack_w_kernel<<<dim3(8 * 16), 256, 0, stream>>>(fc1_w, fc1_w, 512, 512, 16, 1, Wpf1);
  pack_w_kernel<<<dim3(8 * 16), 256, 0, stream>>>(fc2_w, fc2_w, 512, 512, 16, 1, Wpf2);
  bsum_kernel<<<dim3(16), 256, 0, stream>>>(b_ih0, b_hh0, b_ih1, b_hh1, bs0, bs1);
  // zero: flags (16KB) + hp0_1, hp1_1 (1MB) + c0, c1 (2MB) — contiguous
  hipMemsetAsync(wsb + O_CNT, 0, 16384 + 3 * 1024 * KB, stream);

  persist_kernel<<<dim3(256), dim3(256), 0, stream>>>(
      x, Wp0, Wp1, Wpf1, Wpf2, bs0, bs1, fc1_b, fc2_b, fc3_w, fc3_b,
      hp0_0, hp0_1, hp1_0, hp1_1, c0, c1, y1p, out, cnt);
}

// Round 20
// 1505.809 us; speedup vs baseline: 1.2499x; 1.2499x over previous
//
#include <hip/hip_runtime.h>
#include <math.h>

typedef short s16x4 __attribute__((ext_vector_type(4)));
typedef short s16x8 __attribute__((ext_vector_type(8)));
typedef float f32x4 __attribute__((ext_vector_type(4)));
typedef unsigned short us;
typedef unsigned long long ull;

#define WAITVM(N) do { asm volatile("s_waitcnt vmcnt(" #N ")" ::: "memory"); __builtin_amdgcn_sched_barrier(0); } while (0)

namespace {
constexpr int T = 80, Fdim = 32, H = 512, OSTR = 34;
constexpr int CH = 2048;   // us elements per chunk (fp16)

__device__ __forceinline__ us f2h(float f) {
  union { _Float16 h; us u; } x; x.h = (_Float16)f; return x.u;
}
__device__ __forceinline__ float sigf(float v) { return 1.f / (1.f + expf(-v)); }
__device__ __forceinline__ float geluf(float v) {
  return 0.5f * v * (1.f + erff(v * 0.70710678118654752f));
}

__device__ __forceinline__ ull ald8(const void* p) {
  return __hip_atomic_load((const ull*)p, __ATOMIC_RELAXED, __HIP_MEMORY_SCOPE_AGENT);
}
__device__ __forceinline__ void ast8(void* p, ull v) {
  __hip_atomic_store((ull*)p, v, __ATOMIC_RELAXED, __HIP_MEMORY_SCOPE_AGENT);
}
__device__ __forceinline__ void ast4f(float* p, float v) {
  __hip_atomic_store(p, v, __ATOMIC_RELAXED, __HIP_MEMORY_SCOPE_AGENT);
}

union U8 { ull u; s16x4 v4; float f[2]; };
union S8 { s16x8 v; ull u[2]; };

struct SetA { ull a0, a1; };
struct SetB { s16x8 b1, b0; };
struct HSetA { ull a0; };
struct HSetB { s16x8 b0, b1; };

// ---------------- weight pre-pack: single fp16, fragment-linear ----------------
__global__ __launch_bounds__(256)
void pack_w_kernel(const float* __restrict__ w1, const float* __restrict__ w2,
                   int K1, int K2, int NKC, int head, us* __restrict__ dst) {
  int bid = blockIdx.x;
  int jb = bid / NKC, kc = bid % NKC;
  int tid = threadIdx.x;
  int strip = tid >> 6, l = tid & 63;
  int nl = l & 15, kg = l >> 4;
  int n = head ? (jb * 64 + strip * 16 + nl) : (strip * 512 + jb * 16 + nl);
  s16x8 h8;
  #pragma unroll
  for (int i = 0; i < 8; ++i) {
    int k = kc * 32 + kg * 8 + i;
    float v = (k < K1) ? w1[(size_t)n * K1 + k] : w2[(size_t)n * K2 + (k - K1)];
    h8[i] = (short)f2h(v);
  }
  *(s16x8*)&dst[(size_t)bid * CH + strip * 512 + l * 8] = h8;
}

__global__ __launch_bounds__(256)
void bsum_kernel(const float* bi0, const float* bh0, const float* bi1, const float* bh1,
                 float* bs0, float* bs1) {
  int i = blockIdx.x * 256 + threadIdx.x;
  if (i < 2048) bs0[i] = bi0[i] + bh0[i];
  else { int j = i - 2048; bs1[j] = bi1[j] + bh1[j]; }
}

// ---------------- persistent whole-model kernel ----------------
// 256 WGs = 8 groups (64 rows) x 32 WGs (16 h-cols). fp16 datapath.
// Deep A prefetch: 8 register sets, load->LDS-write distance = 2 iterations,
// one __syncthreads per 4 chunks.
__global__ __launch_bounds__(256, 1)
void persist_kernel(const float* __restrict__ x,
                    const us* __restrict__ Wp0, const us* __restrict__ Wp1,
                    const us* __restrict__ Wpf1, const us* __restrict__ Wpf2,
                    const float* __restrict__ bs0, const float* __restrict__ bs1,
                    const float* __restrict__ fc1_b, const float* __restrict__ fc2_b,
                    const float* __restrict__ fc3_w, const float* __restrict__ fc3_b,
                    us* hp0_0, us* hp0_1, us* hp1_0, us* hp1_1,
                    float* c0, float* c1, us* y1p,
                    float* out, int* cnt)
{
  __shared__ __align__(16) us Ash[8][2048];
  __shared__ __align__(16) float Gs[4][64][16];

  const int tid = threadIdx.x;
  const int bid = blockIdx.x;
  const int w = tid >> 6, l = tid & 63;
  const int m = bid >> 5;                      // group 0..7 (64 rows)
  const int lb = bid & 31;                     // group-local WG id
  const int jb = (lb & 7) * 4 + (lb >> 3);     // h-col slice 0..31
  const int row0 = m * 64;
  const int j0 = jb * 16;
  const int base31 = j0 & 31;

  const us* WpJ0 = Wp0 + (size_t)jb * 17 * CH;
  const us* WpJ1 = Wp1 + (size_t)jb * 32 * CH;

  int ph = 0;
  auto garrive = [&]() {
    ++ph;
    WAITVM(0);
    __syncthreads();
    if (tid == 0)
      __hip_atomic_store(&cnt[m * 512 + lb * 16], ph, __ATOMIC_RELEASE,
                         __HIP_MEMORY_SCOPE_AGENT);
  };
  auto gwait = [&]() {
    if (tid < 32) {
      while (__hip_atomic_load(&cnt[m * 512 + tid * 16], __ATOMIC_RELAXED,
                               __HIP_MEMORY_SCOPE_AGENT) < ph)
        __builtin_amdgcn_s_sleep(1);
      __builtin_amdgcn_fence(__ATOMIC_ACQUIRE, "workgroup");
    }
    __syncthreads();
  };

  // ---------- fused LSTM phase: {L1(t-1) if DO1} + {L0(t) if DO0} ----------
  auto fused = [&](bool DO1, bool DO0, int t, bool use_fb, int kidx, bool preh) {
    const us* h0prev = ((t + 1) & 1) ? hp0_1 : hp0_0;
    const us* h1prev = (t & 1) ? hp1_1 : hp1_0;
    us* h1w = ((t + 1) & 1) ? hp1_1 : hp1_0;
    us* h0w = (t & 1) ? hp0_1 : hp0_0;

    f32x4 acc0[4], acc1[4];
    #pragma unroll
    for (int mf = 0; mf < 4; ++mf) {
      acc0[mf] = {0.f, 0.f, 0.f, 0.f};
      acc1[mf] = {0.f, 0.f, 0.f, 0.f};
    }
    const int NP = DO1 ? 32 : 16;
    SetA A0s, A1s, A2s, A3s, A4s, A5s, A6s, A7s;
    SetB B0s, B1s, B2s, B3s;

    auto issA = [&](int c, SetA& R, int hi) {
      if (c >= hi) return;
      const us* a = ((c < 16) ? h0prev : h1prev) + (size_t)(m * 16 + (c & 15)) * CH;
      R.a0 = ald8(a + tid * 8);
      R.a1 = ald8(a + tid * 8 + 4);
    };
    auto issB = [&](int c, SetB& R, int hi) {
      if (c >= hi) return;
      if (DO1) R.b1 = *(const s16x8*)(WpJ1 + (size_t)c * CH + w * 512 + l * 8);
      if (DO0 && c < 16)
        R.b0 = *(const s16x8*)(WpJ0 + (size_t)(c + 1) * CH + w * 512 + l * 8);
    };
    auto wrtA = [&](int c, SetA& R, int hi) {
      if (c >= hi) return;
      int sl = c & 7;
      *(ull*)&Ash[sl][tid * 8] = R.a0;
      *(ull*)&Ash[sl][tid * 8 + 4] = R.a1;
    };
    auto lcomp = [&](int kc, SetB& B, bool c1on, bool c0on) {
      int sl = kc & 7;
      #pragma unroll
      for (int mf = 0; mf < 4; ++mf) {
        s16x8 Ah = *(const s16x8*)&Ash[sl][mf * 512 + l * 8];
        if (c1on)
          acc1[mf] = __builtin_amdgcn_mfma_f32_16x16x32_f16(Ah, B.b1, acc1[mf], 0, 0, 0);
        if (c0on)
          acc0[mf] = __builtin_amdgcn_mfma_f32_16x16x32_f16(Ah, B.b0, acc0[mf], 0, 0, 0);
      }
    };

    // lo/hi multiples of 8. Chunk c -> A set (c-lo)&7, LDS slot c&7, B set c&3.
    auto runseg = [&](int lo, int hi) {
      issA(lo + 0, A0s, hi); issA(lo + 1, A1s, hi);
      issA(lo + 2, A2s, hi); issA(lo + 3, A3s, hi);
      issA(lo + 4, A4s, hi); issA(lo + 5, A5s, hi);
      issA(lo + 6, A6s, hi); issA(lo + 7, A7s, hi);
      wrtA(lo + 0, A0s, hi); wrtA(lo + 1, A1s, hi);
      wrtA(lo + 2, A2s, hi); wrtA(lo + 3, A3s, hi);
      issA(lo + 8, A0s, hi); issA(lo + 9, A1s, hi);
      issA(lo + 10, A2s, hi); issA(lo + 11, A3s, hi);
      __syncthreads();
      for (int base = lo; base < hi; base += 8) {
        // iter A: compute base..base+3
        { int kc = base + 0; lcomp(kc, B0s, DO1, DO0 && kc < 16); issB(kc + 4, B0s, hi); }
        { int kc = base + 1; lcomp(kc, B1s, DO1, DO0 && kc < 16); issB(kc + 4, B1s, hi); }
        { int kc = base + 2; lcomp(kc, B2s, DO1, DO0 && kc < 16); issB(kc + 4, B2s, hi); }
        { int kc = base + 3; lcomp(kc, B3s, DO1, DO0 && kc < 16); issB(kc + 4, B3s, hi); }
        wrtA(base + 4, A4s, hi); wrtA(base + 5, A5s, hi);
        wrtA(base + 6, A6s, hi); wrtA(base + 7, A7s, hi);
        issA(base + 12, A4s, hi); issA(base + 13, A5s, hi);
        issA(base + 14, A6s, hi); issA(base + 15, A7s, hi);
        __syncthreads();
        // iter B: compute base+4..base+7
        { int kc = base + 4; lcomp(kc, B0s, DO1, DO0 && kc < 16); issB(kc + 4, B0s, hi); }
        { int kc = base + 5; lcomp(kc, B1s, DO1, DO0 && kc < 16); issB(kc + 4, B1s, hi); }
        { int kc = base + 6; lcomp(kc, B2s, DO1, DO0 && kc < 16); issB(kc + 4, B2s, hi); }
        { int kc = base + 7; lcomp(kc, B3s, DO1, DO0 && kc < 16); issB(kc + 4, B3s, hi); }
        wrtA(base + 8, A0s, hi); wrtA(base + 9, A1s, hi);
        wrtA(base + 10, A2s, hi); wrtA(base + 11, A3s, hi);
        issA(base + 16, A0s, hi); issA(base + 17, A1s, hi);
        issA(base + 18, A2s, hi); issA(base + 19, A3s, hi);
        __syncthreads();
      }
    };

    if (preh) {
      if (DO1) {
        issB(16, B0s, 32); issB(17, B1s, 32); issB(18, B2s, 32); issB(19, B3s, 32);
        runseg(16, 32);
        issB(0, B0s, 16); issB(1, B1s, 16); issB(2, B2s, 16); issB(3, B3s, 16);
        gwait();
        runseg(0, 16);
      } else {
        issB(0, B0s, 16); issB(1, B1s, 16); issB(2, B2s, 16); issB(3, B3s, 16);
        runseg(0, 16);
        gwait();
      }
    } else {
      issB(0, B0s, NP); issB(1, B1s, NP); issB(2, B2s, NP); issB(3, B3s, NP);
      gwait();
      runseg(0, NP);
    }

    if (DO0) {  // x chunk (L0 weight chunk 0) — post-barrier (feedback)
      SetB Bx;
      Bx.b0 = *(const s16x8*)(WpJ0 + w * 512 + l * 8);
      int srow = tid >> 2, skg = tid & 3;
      const float* xp = x + (size_t)(row0 + srow) * (T * Fdim) + (size_t)t * Fdim + skg * 8;
      float v[8];
      #pragma unroll
      for (int i = 0; i < 8; ++i) v[i] = xp[i];
      if (use_fb && skg == 0) {
        const float* op = out + (size_t)(row0 + srow) * OSTR + kidx * 2;
        v[4] = __hip_atomic_load(op, __ATOMIC_RELAXED, __HIP_MEMORY_SCOPE_AGENT);
        v[5] = __hip_atomic_load(op + 1, __ATOMIC_RELAXED, __HIP_MEMORY_SCOPE_AGENT);
      }
      s16x8 h8;
      #pragma unroll
      for (int i = 0; i < 8; ++i) h8[i] = (short)f2h(v[i]);
      int slane = skg * 16 + (srow & 15), smf = srow >> 4;
      *(s16x8*)&Ash[0][smf * 512 + slane * 8] = h8;
      __syncthreads();
      lcomp(0, Bx, false, true);
    }

    // epilogue: stash gates -> cell -> packed coherent h write (fp16)
    auto epi = [&](f32x4* acc, const float* bsum, float* cst, us* hw) {
      __syncthreads();
      float bsv = bsum[w * 512 + j0 + (l & 15)];
      #pragma unroll
      for (int mf = 0; mf < 4; ++mf)
        #pragma unroll
        for (int r = 0; r < 4; ++r)
          Gs[w][mf * 16 + (l >> 4) * 4 + r][l & 15] = acc[mf][r] + bsv;
      __syncthreads();
      int r = tid >> 2, sub = tid & 3, cc0 = sub * 4;
      float gvi[4], gvf[4], gvg[4], gvo[4], cv[4], cn[4], hv[4];
      #pragma unroll
      for (int q = 0; q < 4; ++q) {
        gvi[q] = Gs[0][r][cc0 + q]; gvf[q] = Gs[1][r][cc0 + q];
        gvg[q] = Gs[2][r][cc0 + q]; gvo[q] = Gs[3][r][cc0 + q];
      }
      size_t cix = (size_t)(row0 + r) * H + j0 + cc0;
      float4 cold = *(const float4*)&cst[cix];
      cv[0] = cold.x; cv[1] = cold.y; cv[2] = cold.z; cv[3] = cold.w;
      #pragma unroll
      for (int q = 0; q < 4; ++q) {
        float c2 = sigf(gvf[q]) * cv[q] + sigf(gvi[q]) * tanhf(gvg[q]);
        cn[q] = c2;
        hv[q] = sigf(gvo[q]) * tanhf(c2);
      }
      *(float4*)&cst[cix] = make_float4(cn[0], cn[1], cn[2], cn[3]);
      int kk = base31 + cc0;
      int kg = kk >> 3, i0 = kk & 7;
      int mf = r >> 4;
      int lane2 = kg * 16 + (r & 15);
      us* bb = hw + (size_t)(m * 16 + (j0 >> 5)) * CH;
      U8 hh;
      #pragma unroll
      for (int q = 0; q < 4; ++q) hh.v4[q] = (short)f2h(hv[q]);
      ast8(bb + (size_t)mf * 512 + lane2 * 8 + i0, hh.u);
      __syncthreads();
    };
    if (DO1) epi(acc1, bs1, c1, h1w);
    if (DO0) epi(acc0, bs0, c0, h0w);
  };

  // ---------- head GEMM: 16 of 32 WGs, 32 rows x 64 cols (r18-identical) ----------
  auto headg = [&](const us* apack, const us* Wp, const float* bias,
                   us* yp, int kidx) {
    if (lb < 16) {
      const int mhl = lb >> 3, cb = lb & 7;
      const int hrow0 = row0 + mhl * 32, hj0 = cb * 64;
      const int wm = w >> 1, wn = w & 1;
      f32x4 hacc[2];
      hacc[0] = {0.f, 0.f, 0.f, 0.f};
      hacc[1] = {0.f, 0.f, 0.f, 0.f};
      HSetA HA0, HA1, HA2, HA3;
      HSetB HB0, HB1;
      auto hissA = [&](int c, HSetA& R) {
        if (c >= 16) return;
        const us* a = apack + (size_t)(m * 16 + c) * CH + mhl * 1024;
        R.a0 = ald8(a + tid * 4);
      };
      auto hissB = [&](int c, HSetB& R) {
        if (c >= 16) return;
        const us* b = Wp + (size_t)(cb * 16 + c) * CH + wn * 1024 + l * 8;
        R.b0 = *(const s16x8*)(b);
        R.b1 = *(const s16x8*)(b + 512);
      };
      auto hwrtA = [&](int c, HSetA& R) {
        if (c >= 16) return;
        int sl = c % 3;
        *(ull*)&Ash[sl][tid * 4] = R.a0;
      };
      auto hcmp = [&](int sl, HSetB& B) {
        s16x8 Ah = *(const s16x8*)&Ash[sl][wm * 512 + l * 8];
        hacc[0] = __builtin_amdgcn_mfma_f32_16x16x32_f16(Ah, B.b0, hacc[0], 0, 0, 0);
        hacc[1] = __builtin_amdgcn_mfma_f32_16x16x32_f16(Ah, B.b1, hacc[1], 0, 0, 0);
      };
      hissA(0, HA0); hissA(1, HA1); hissA(2, HA2); hissA(3, HA3);
      hwrtA(0, HA0); hissA(4, HA0);
      hwrtA(1, HA1); hissA(5, HA1);
      hissB(0, HB0); hissB(1, HB1);
      __syncthreads();
      for (int base = 0; base < 16; base += 4) {
        { int kc = base + 0; hcmp(kc % 3, HB0); hissB(kc + 2, HB0);
          hwrtA(kc + 2, HA2); hissA(kc + 6, HA2); __syncthreads(); }
        { int kc = base + 1; hcmp(kc % 3, HB1); hissB(kc + 2, HB1);
          hwrtA(kc + 2, HA3); hissA(kc + 6, HA3); __syncthreads(); }
        { int kc = base + 2; hcmp(kc % 3, HB0); hissB(kc + 2, HB0);
          hwrtA(kc + 2, HA0); hissA(kc + 6, HA0); __syncthreads(); }
        { int kc = base + 3; hcmp(kc % 3, HB1); hissB(kc + 2, HB1);
          hwrtA(kc + 2, HA1); hissA(kc + 6, HA1); __syncthreads(); }
      }
      __syncthreads();
      float* GsF = (float*)Gs;
      #pragma unroll
      for (int nf = 0; nf < 2; ++nf)
        #pragma unroll
        for (int rq = 0; rq < 4; ++rq) {
          int rr = wm * 16 + (l >> 4) * 4 + rq;
          int ccl = wn * 32 + nf * 16 + (l & 15);
          GsF[rr * 64 + ccl] = geluf(hacc[nf][rq] + bias[hj0 + ccl]);
        }
      __syncthreads();
      if (yp) {
        int chunk = tid >> 7, tt = tid & 127;
        int mf_loc = tt >> 6, lane = tt & 63;
        int row = mf_loc * 16 + (lane & 15);
        int kg = lane >> 4;
        S8 hv;
        #pragma unroll
        for (int i = 0; i < 8; ++i)
          hv.v[i] = (short)f2h(GsF[row * 64 + chunk * 32 + kg * 8 + i]);
        us* dst = yp + ((size_t)m * 16 + (cb * 2 + chunk)) * CH;
        ast8(dst + (size_t)(mhl * 2 + mf_loc) * 512 + lane * 8, hv.u[0]);
        ast8(dst + (size_t)(mhl * 2 + mf_loc) * 512 + lane * 8 + 4, hv.u[1]);
      } else {
        int r = tid >> 3, cg = tid & 7;
        float p0 = 0.f, p1 = 0.f;
        #pragma unroll
        for (int i = 0; i < 8; ++i) {
          float yv = GsF[r * 64 + cg * 8 + i];
          int col = hj0 + cg * 8 + i;
          p0 += yv * fc3_w[col];
          p1 += yv * fc3_w[512 + col];
        }
        #pragma unroll
        for (int d = 4; d > 0; d >>= 1) {
          p0 += __shfl_down(p0, d, 8);
          p1 += __shfl_down(p1, d, 8);
        }
        if (cg == 0) {
          atomicAdd(out + (size_t)(hrow0 + r) * OSTR + kidx * 2, p0);
          atomicAdd(out + (size_t)(hrow0 + r) * OSTR + kidx * 2 + 1, p1);
        }
      }
      __syncthreads();
    }
  };

  auto h1buf = [&](int t) { return (t & 1) ? hp1_1 : hp1_0; };

  // ================= schedule (8 independent groups) =================
  fused(false, true, 0, false, 0, true); garrive();          // t=0 (pre-safe)
  for (int t = 1; t < 64; ++t) { fused(true, true, t, false, 0, false); garrive(); }
  fused(true, false, 64, false, 0, false); garrive();        // L1(63)

  for (int kidx = 0; kidx < 17; ++kidx) {
    const us* h1cur = h1buf(63 + kidx);
    gwait();
    headg(h1cur, Wpf1, fc1_b, y1p, kidx);
    if (lb == 16 && tid < 128) {
      int r2 = tid >> 1, o = tid & 1;
      ast4f(out + (size_t)(row0 + r2) * OSTR + kidx * 2 + o, fc3_b[o]);
    }
    garrive();
    gwait();
    headg(y1p, Wpf2, fc2_b, nullptr, kidx);
    garrive();
    if (kidx < 16) {
      fused(false, true, 64 + kidx, true, kidx, true); garrive();
      fused(true, false, 65 + kidx, false, 0, true); garrive();
    }
  }
}

} // namespace

extern "C" void kernel_launch(void* const* d_in, const int* in_sizes, int n_in,
                              void* d_out, int out_size, void* d_ws, size_t ws_size,
                              hipStream_t stream) {
  const float* x     = (const float*)d_in[0];
  const float* w_ih0 = (const float*)d_in[1];
  const float* w_hh0 = (const float*)d_in[2];
  const float* b_ih0 = (const float*)d_in[3];
  const float* b_hh0 = (const float*)d_in[4];
  const float* w_ih1 = (const float*)d_in[5];
  const float* w_hh1 = (const float*)d_in[6];
  const float* b_ih1 = (const float*)d_in[7];
  const float* b_hh1 = (const float*)d_in[8];
  const float* fc1_w = (const float*)d_in[9];
  const float* fc1_b = (const float*)d_in[10];
  const float* fc2_w = (const float*)d_in[11];
  const float* fc2_b = (const float*)d_in[12];
  const float* fc3_w = (const float*)d_in[13];
  const float* fc3_b = (const float*)d_in[14];
  float* out = (float*)d_out;
  char* wsb = (char*)d_ws;

  constexpr size_t KB = 1024;
  constexpr size_t O_WP0  = 0;                          // 32*17*4KB
  constexpr size_t O_WP1  = 2228224;                    // 32*32*4KB
  constexpr size_t O_WPF1 = O_WP1 + 4194304;
  constexpr size_t O_WPF2 = O_WPF1 + 524288;
  constexpr size_t O_BS0  = O_WPF2 + 524288;
  constexpr size_t O_BS1  = O_BS0 + 8192;
  constexpr size_t O_CNT  = O_BS1 + 8192;               // flags 16 KB
  constexpr size_t O_HP0B = O_CNT + 16384;              // hp0_1 (zeroed)
  constexpr size_t O_HP1B = O_HP0B + 512 * KB;          // hp1_1 (zeroed)
  constexpr size_t O_C0   = O_HP1B + 512 * KB;          // c0 (zeroed)
  constexpr size_t O_C1   = O_C0 + 1024 * KB;           // c1 (zeroed)
  constexpr size_t O_HP0A = O_C1 + 1024 * KB;
  constexpr size_t O_HP1A = O_HP0A + 512 * KB;
  constexpr size_t O_Y1P  = O_HP1A + 512 * KB;

  us* Wp0  = (us*)(wsb + O_WP0);
  us* Wp1  = (us*)(wsb + O_WP1);
  us* Wpf1 = (us*)(wsb + O_WPF1);
  us* Wpf2 = (us*)(wsb + O_WPF2);
  float* bs0 = (float*)(wsb + O_BS0);
  float* bs1 = (float*)(wsb + O_BS1);
  int* cnt   = (int*)(wsb + O_CNT);
  us* hp0_1 = (us*)(wsb + O_HP0B);
  us* hp1_1 = (us*)(wsb + O_HP1B);
  float* c0 = (float*)(wsb + O_C0);
  float* c1 = (float*)(wsb + O_C1);
  us* hp0_0 = (us*)(wsb + O_HP0A);
  us* hp1_0 = (us*)(wsb + O_HP1A);
  us* y1p   = (us*)(wsb + O_Y1P);

  pack_w_kernel<<<dim3(32 * 17), 256, 0, stream>>>(w_ih0, w_hh0, 32, 512, 17, 0, Wp0);
  pack_w_kernel<<<dim3(32 * 32), 256, 0, stream>>>(w_ih1, w_hh1, 512, 512, 32, 0, Wp1);
  pack_w_kernel<<<dim3(8 * 16), 256, 0, stream>>>(fc1_w, fc1_w, 512, 512, 16, 1, Wpf1);
  pack_w_kernel<<<dim3(8 * 16), 256, 0, stream>>>(fc2_w, fc2_w, 512, 512, 16, 1, Wpf2);
  bsum_kernel<<<dim3(16), 256, 0, stream>>>(b_ih0, b_hh0, b_ih1, b_hh1, bs0, bs1);
  // zero: flags (16KB) + hp0_1, hp1_1 (1MB) + c0, c1 (2MB) — contiguous
  hipMemsetAsync(wsb + O_CNT, 0, 16384 + 3 * 1024 * KB, stream);

  persist_kernel<<<dim3(256), dim3(256), 0, stream>>>(
      x, Wp0, Wp1, Wpf1, Wpf2, bs0, bs1, fc1_b, fc2_b, fc3_w, fc3_b,
      hp0_0, hp0_1, hp1_0, hp1_1, c0, c1, y1p, out, cnt);
}